// Round 1
// baseline (1260.394 us; speedup 1.0000x reference)
//
#include <hip/hip_runtime.h>

#define B_SZ 32768
#define M_SZ 4
#define D_SZ 256
#define SCALE_Q 0.17677669529663687f   // 1/sqrt(32)

// bf16 weight-region offsets (elements) inside wsW
#define OWQ 0
#define OWK 262144
#define OWV 524288
#define OWO 786432
#define OG1 1048576
#define OF1 1179648
#define OF2 2228224
#define NW_TOT 3276800

typedef __attribute__((ext_vector_type(8))) short bf16x8;
typedef __attribute__((ext_vector_type(4))) float f32x4;

__device__ __forceinline__ short f2b(float f){
  unsigned u = __float_as_uint(f);
  return (short)((u + 0x7FFFu + ((u >> 16) & 1u)) >> 16);
}
__device__ __forceinline__ float b2f(short s){
  return __uint_as_float(((unsigned)(unsigned short)s) << 16);
}
__device__ __forceinline__ float bflo(unsigned u){ return __uint_as_float(u << 16); }
__device__ __forceinline__ float bfhi(unsigned u){ return __uint_as_float(u & 0xFFFF0000u); }
__device__ __forceinline__ unsigned pack2(float a, float b){
  return (unsigned)(unsigned short)f2b(a) | (((unsigned)(unsigned short)f2b(b)) << 16);
}

// ---------------- K0: cast weights to bf16 in workspace ----------------
__global__ void k_cast_w(const float* __restrict__ Wq, const float* __restrict__ Wk,
                         const float* __restrict__ Wv, const float* __restrict__ Wo,
                         const float* __restrict__ g1w, const float* __restrict__ f1w,
                         const float* __restrict__ f2w, short* __restrict__ wsW){
  int i = blockIdx.x * 256 + threadIdx.x;
  if (i >= NW_TOT) return;
  const float* src; int off;
  if (i < OG1){ int r = i >> 18; off = i & 262143;
    src = (r == 0) ? Wq : (r == 1) ? Wk : (r == 2) ? Wv : Wo; }
  else if (i < OF1){ src = g1w; off = i - OG1; }
  else if (i < OF2){ src = f1w; off = i - OF1; }
  else { src = f2w; off = i - OF2; }
  wsW[i] = f2b(src[off]);
}

// helper: 64-row GEMM [64 x 256] = xb(64x256) @ W[m]^T (+bias) -> kv_s  (K or V)
__device__ __forceinline__ void kv_gemm(const short* __restrict__ wmat, const float* __restrict__ bias,
                                        const short* xb_s, short* kv_s, int w, int cl, int kb){
  f32x4 acc[4][2];
#pragma unroll
  for (int rt = 0; rt < 4; ++rt)
#pragma unroll
    for (int c = 0; c < 2; ++c) acc[rt][c] = (f32x4){0.f,0.f,0.f,0.f};
  for (int kk = 0; kk < 8; ++kk){
    bf16x8 a[4];
#pragma unroll
    for (int rt = 0; rt < 4; ++rt)
      a[rt] = *(const bf16x8*)&xb_s[(rt*16 + cl)*264 + kk*32 + kb*8];
#pragma unroll
    for (int c = 0; c < 2; ++c){
      int col = (2*w + c)*16 + cl;
      bf16x8 b = *(const bf16x8*)&wmat[(size_t)col*256 + kk*32 + kb*8];
#pragma unroll
      for (int rt = 0; rt < 4; ++rt)
        acc[rt][c] = __builtin_amdgcn_mfma_f32_16x16x32_bf16(a[rt], b, acc[rt][c], 0, 0, 0);
    }
  }
#pragma unroll
  for (int c = 0; c < 2; ++c){
    int col = (2*w + c)*16 + cl;
    float bs = bias[col];
#pragma unroll
    for (int rt = 0; rt < 4; ++rt)
#pragma unroll
      for (int i = 0; i < 4; ++i)
        kv_s[(rt*16 + kb*4 + i)*264 + col] = f2b(acc[rt][c][i] + bs);
  }
}

// ---------------- K1: fused Q/K/V + attention + Wo + gate + LN ----------------
__global__ __launch_bounds__(512, 1)
void k_attn(const float* __restrict__ x, const short* __restrict__ wsW,
            const float* __restrict__ bq, const float* __restrict__ bk,
            const float* __restrict__ bv, const float* __restrict__ bo,
            const float* __restrict__ g1b, const float* __restrict__ g2w,
            const float* __restrict__ g2b, const float* __restrict__ ln_g,
            const float* __restrict__ ln_b, short* __restrict__ wsY,
            float* __restrict__ gate_out)
{
  __shared__ __align__(16) short xb_s[64*264];   // x tile, rows = (b_loc*4 + mod)
  __shared__ __align__(16) short q_s [64*264];   // Q (scaled) -> later Oh
  __shared__ __align__(16) short kv_s[64*264];   // K -> V -> attn_out
  __shared__ float aw_s[16][8][4];
  __shared__ float gp_s[8][16];
  __shared__ float gate_s[64];

  const int tid = threadIdx.x;
  const int rb  = blockIdx.x * 64;               // global row base (= b0*4)
  const int w   = tid >> 6, l = tid & 63;
  const int cl  = l & 15, kb = l >> 4;

  // ---- phase 0: stage x tile fp32 -> bf16 LDS ----
  {
    int r = tid >> 3, s = tid & 7;
    const float4* gp4 = (const float4*)(x + (size_t)(rb + r) * 256);
    unsigned* dst = (unsigned*)&xb_s[r*264];
#pragma unroll
    for (int j = 0; j < 8; ++j){
      float4 v = gp4[j*8 + s];
      int c = (j*8 + s)*4;
      dst[(c >> 1)    ] = pack2(v.x, v.y);
      dst[(c >> 1) + 1] = pack2(v.z, v.w);
    }
  }
  __syncthreads();

  // ---- phase 1: Q GEMM (per-wave modality), scaled, -> q_s ----
  {
    const int m = w & 3, half = w >> 2;
    const short* wq = wsW + OWQ + m*65536;
    f32x4 acc[8];
#pragma unroll
    for (int ct = 0; ct < 8; ++ct) acc[ct] = (f32x4){0.f,0.f,0.f,0.f};
    for (int kk = 0; kk < 8; ++kk){
      bf16x8 a = *(const bf16x8*)&xb_s[(4*cl + m)*264 + kk*32 + kb*8];
#pragma unroll
      for (int ct = 0; ct < 8; ++ct){
        int col = half*128 + ct*16 + cl;
        bf16x8 b = *(const bf16x8*)&wq[(size_t)col*256 + kk*32 + kb*8];
        acc[ct] = __builtin_amdgcn_mfma_f32_16x16x32_bf16(a, b, acc[ct], 0, 0, 0);
      }
    }
#pragma unroll
    for (int ct = 0; ct < 8; ++ct){
      int col = half*128 + ct*16 + cl;
      float bs = bq[m*256 + col];
#pragma unroll
      for (int i = 0; i < 4; ++i)
        q_s[(4*(kb*4 + i) + m)*264 + col] = f2b((acc[ct][i] + bs) * SCALE_Q);
    }
  }
  __syncthreads();

  // ---- phase 2: per modality mm: K -> scores/softmax -> V -> Oh ----
  for (int mm = 0; mm < 4; ++mm){
    kv_gemm(wsW + OWK + mm*65536, bk + mm*256, xb_s, kv_s, w, cl, kb);
    __syncthreads();
    {  // scores + softmax: one thread per (b_loc, h, n)
      int bl = tid >> 5, h = (tid >> 2) & 7, n = tid & 3;
      const unsigned* qp = (const unsigned*)&q_s [(4*bl + mm)*264 + h*32];
      const unsigned* kp = (const unsigned*)&kv_s[(4*bl + n )*264 + h*32];
      float s = 0.f;
#pragma unroll
      for (int j = 0; j < 16; ++j){
        unsigned uq = qp[j], uk = kp[j];
        s += bflo(uq)*bflo(uk) + bfhi(uq)*bfhi(uk);
      }
      float mx = fmaxf(s, __shfl_xor(s, 1));
      mx = fmaxf(mx, __shfl_xor(mx, 2));
      float e = expf(s - mx);
      float sum = e + __shfl_xor(e, 1);
      sum += __shfl_xor(sum, 2);
      aw_s[bl][h][n] = e / sum;
    }
    __syncthreads();
    kv_gemm(wsW + OWV + mm*65536, bv + mm*256, xb_s, kv_s, w, cl, kb);
    __syncthreads();
    {  // Oh = sum_n A * V  -> overwrite q_s row (4*bl+mm)
      int bl = tid >> 5, c8 = tid & 31, h = c8 >> 2;
      float oh[8];
#pragma unroll
      for (int j = 0; j < 8; ++j) oh[j] = 0.f;
#pragma unroll
      for (int n = 0; n < 4; ++n){
        float an = aw_s[bl][h][n];
        const unsigned* vp = (const unsigned*)&kv_s[(4*bl + n)*264 + c8*8];
#pragma unroll
        for (int jj = 0; jj < 4; ++jj){
          unsigned u = vp[jj];
          oh[2*jj  ] += an * bflo(u);
          oh[2*jj+1] += an * bfhi(u);
        }
      }
      unsigned* op = (unsigned*)&q_s[(4*bl + mm)*264 + c8*8];
#pragma unroll
      for (int jj = 0; jj < 4; ++jj) op[jj] = pack2(oh[2*jj], oh[2*jj+1]);
    }
    __syncthreads();
  }

  // ---- phase 3: attn_out = Oh @ Wo^T + bo  -> kv_s ----
  {
    const int m = w & 3, half = w >> 2;
    const short* wo = wsW + OWO + m*65536;
    f32x4 acc[8];
#pragma unroll
    for (int ct = 0; ct < 8; ++ct) acc[ct] = (f32x4){0.f,0.f,0.f,0.f};
    for (int kk = 0; kk < 8; ++kk){
      bf16x8 a = *(const bf16x8*)&q_s[(4*cl + m)*264 + kk*32 + kb*8];
#pragma unroll
      for (int ct = 0; ct < 8; ++ct){
        int col = half*128 + ct*16 + cl;
        bf16x8 b = *(const bf16x8*)&wo[(size_t)col*256 + kk*32 + kb*8];
        acc[ct] = __builtin_amdgcn_mfma_f32_16x16x32_bf16(a, b, acc[ct], 0, 0, 0);
      }
    }
#pragma unroll
    for (int ct = 0; ct < 8; ++ct){
      int col = half*128 + ct*16 + cl;
      float bs = bo[m*256 + col];
#pragma unroll
      for (int i = 0; i < 4; ++i)
        kv_s[(4*(kb*4 + i) + m)*264 + col] = f2b(acc[ct][i] + bs);
    }
  }
  __syncthreads();

  // ---- phase 4: gate MLP layer-1 GEMM (K=512 over [x ; attn]) + tanh + g2 partial ----
  {
    const int m = w & 3, half = w >> 2;
    const short* g1 = wsW + OG1 + m*32768;
    f32x4 acc[2];
    acc[0] = (f32x4){0.f,0.f,0.f,0.f};
    acc[1] = (f32x4){0.f,0.f,0.f,0.f};
    for (int kk = 0; kk < 16; ++kk){
      const short* ab = (kk < 8) ? &xb_s[(4*cl + m)*264 + kk*32 + kb*8]
                                 : &kv_s[(4*cl + m)*264 + (kk - 8)*32 + kb*8];
      bf16x8 a = *(const bf16x8*)ab;
#pragma unroll
      for (int c = 0; c < 2; ++c){
        int col = half*32 + c*16 + cl;
        bf16x8 b = *(const bf16x8*)&g1[(size_t)col*512 + kk*32 + kb*8];
        acc[c] = __builtin_amdgcn_mfma_f32_16x16x32_bf16(a, b, acc[c], 0, 0, 0);
      }
    }
    float p[4] = {0.f, 0.f, 0.f, 0.f};
#pragma unroll
    for (int c = 0; c < 2; ++c){
      int col = half*32 + c*16 + cl;
      float b1 = g1b[m*64 + col], w2 = g2w[m*64 + col];
#pragma unroll
      for (int i = 0; i < 4; ++i) p[i] += tanhf(acc[c][i] + b1) * w2;
    }
#pragma unroll
    for (int i = 0; i < 4; ++i){
      p[i] += __shfl_xor(p[i], 1);
      p[i] += __shfl_xor(p[i], 2);
      p[i] += __shfl_xor(p[i], 4);
      p[i] += __shfl_xor(p[i], 8);
    }
    if (cl == 0){
#pragma unroll
      for (int i = 0; i < 4; ++i) gp_s[w][kb*4 + i] = p[i];
    }
  }
  __syncthreads();

  // ---- phase 5a: finalize gate + write gate output ----
  if (tid < 64){
    int bl = tid >> 2, m = tid & 3;
    float logit = gp_s[m][bl] + gp_s[m + 4][bl] + g2b[m];
    float g = 1.f / (1.f + expf(-logit));
    gate_s[tid] = g;
    gate_out[rb + tid] = g;
  }
  __syncthreads();

  // ---- phase 5b: residual + LayerNorm -> wsY (bf16) ----
  {
    int r = tid >> 3, sg = tid & 7, m = r & 3;
    float g = gate_s[r];
    const unsigned* xp = (const unsigned*)&xb_s[r*264 + sg*32];
    const unsigned* ap = (const unsigned*)&kv_s[r*264 + sg*32];
    float rv[32];
    float sum = 0.f, sq = 0.f;
#pragma unroll
    for (int j = 0; j < 16; ++j){
      unsigned ux = xp[j], ua = ap[j];
      float v0 = bflo(ux) + g*bflo(ua);
      float v1 = bfhi(ux) + g*bfhi(ua);
      rv[2*j] = v0; rv[2*j+1] = v1;
      sum += v0 + v1; sq += v0*v0 + v1*v1;
    }
#pragma unroll
    for (int o = 1; o < 8; o <<= 1){
      sum += __shfl_xor(sum, o);
      sq  += __shfl_xor(sq, o);
    }
    float mu  = sum * (1.f/256.f);
    float var = sq * (1.f/256.f) - mu*mu;
    float rstd = rsqrtf(var + 1e-5f);
    unsigned* yp = (unsigned*)(wsY + (size_t)(rb + r)*256 + sg*32);
#pragma unroll
    for (int j = 0; j < 16; ++j){
      int c = sg*32 + 2*j;
      float y0 = (rv[2*j]   - mu)*rstd*ln_g[m*256 + c    ] + ln_b[m*256 + c    ];
      float y1 = (rv[2*j+1] - mu)*rstd*ln_g[m*256 + c + 1] + ln_b[m*256 + c + 1];
      yp[j] = pack2(y0, y1);
    }
  }
}

// ---------------- K2: fused FeedForward (f1 + exact GELU + f2 + residual) ----------------
__global__ __launch_bounds__(512, 1)
void k_ff(const short* __restrict__ wsY, const short* __restrict__ wsW,
          const float* __restrict__ f1bias, const float* __restrict__ f2bias,
          float* __restrict__ out)
{
  __shared__ __align__(16) short y_s [128*264];
  __shared__ __align__(16) short hf_s[128*264];
  const int tid = threadIdx.x;
  const int m  = blockIdx.x >> 8;
  const int b0 = (blockIdx.x & 255) * 128;
  const int w = tid >> 6, l = tid & 63, cl = l & 15, kb = l >> 4;
  const int rh = w >> 2, cq = w & 3;

  {  // stage y tile (rows of modality m, stride-4 in global)
    int r = tid >> 2, qq = tid & 3;
    const short* src = wsY + ((size_t)(b0 + r)*4 + m)*256 + qq*64;
#pragma unroll
    for (int j = 0; j < 8; ++j)
      *(bf16x8*)&y_s[r*264 + qq*64 + j*8] = *(const bf16x8*)(src + j*8);
  }
  __syncthreads();

  f32x4 accO[4][4];
#pragma unroll
  for (int rt = 0; rt < 4; ++rt)
#pragma unroll
    for (int ct = 0; ct < 4; ++ct) accO[rt][ct] = (f32x4){0.f,0.f,0.f,0.f};

  for (int ch = 0; ch < 4; ++ch){
    f32x4 acc1[4][4];
#pragma unroll
    for (int rt = 0; rt < 4; ++rt)
#pragma unroll
      for (int ct = 0; ct < 4; ++ct) acc1[rt][ct] = (f32x4){0.f,0.f,0.f,0.f};
    for (int kk = 0; kk < 8; ++kk){
      bf16x8 a[4];
#pragma unroll
      for (int rt = 0; rt < 4; ++rt)
        a[rt] = *(const bf16x8*)&y_s[(rh*64 + rt*16 + cl)*264 + kk*32 + kb*8];
#pragma unroll
      for (int ct = 0; ct < 4; ++ct){
        size_t ncol = (size_t)(ch*256 + cq*64 + ct*16 + cl);
        bf16x8 b = *(const bf16x8*)&wsW[OF1 + (size_t)m*262144 + ncol*256 + kk*32 + kb*8];
#pragma unroll
        for (int rt = 0; rt < 4; ++rt)
          acc1[rt][ct] = __builtin_amdgcn_mfma_f32_16x16x32_bf16(a[rt], b, acc1[rt][ct], 0, 0, 0);
      }
    }
    // exact GELU -> hf_s
#pragma unroll
    for (int ct = 0; ct < 4; ++ct){
      int ncl = cq*64 + ct*16 + cl;
      float bs = f1bias[m*1024 + ch*256 + ncl];
#pragma unroll
      for (int rt = 0; rt < 4; ++rt)
#pragma unroll
        for (int i = 0; i < 4; ++i){
          float v = acc1[rt][ct][i] + bs;
          float gv = 0.5f * v * (1.f + erff(v * 0.70710678118654752f));
          hf_s[(rh*64 + rt*16 + kb*4 + i)*264 + ncl] = f2b(gv);
        }
    }
    __syncthreads();
    // f2 partial accumulate
    for (int kk = 0; kk < 8; ++kk){
      bf16x8 a[4];
#pragma unroll
      for (int rt = 0; rt < 4; ++rt)
        a[rt] = *(const bf16x8*)&hf_s[(rh*64 + rt*16 + cl)*264 + kk*32 + kb*8];
#pragma unroll
      for (int ct = 0; ct < 4; ++ct){
        size_t ocol = (size_t)(cq*64 + ct*16 + cl);
        bf16x8 b = *(const bf16x8*)&wsW[OF2 + (size_t)m*262144 + ocol*1024 + ch*256 + kk*32 + kb*8];
#pragma unroll
        for (int rt = 0; rt < 4; ++rt)
          accO[rt][ct] = __builtin_amdgcn_mfma_f32_16x16x32_bf16(a[rt], b, accO[rt][ct], 0, 0, 0);
      }
    }
    __syncthreads();
  }

  // epilogue: updated = y + ff + f2b
#pragma unroll
  for (int ct = 0; ct < 4; ++ct){
    int col = cq*64 + ct*16 + cl;
    float bs = f2bias[m*256 + col];
#pragma unroll
    for (int rt = 0; rt < 4; ++rt)
#pragma unroll
      for (int i = 0; i < 4; ++i){
        int row = rh*64 + rt*16 + kb*4 + i;
        float val = accO[rt][ct][i] + bs + b2f(y_s[row*264 + col]);
        out[((size_t)(b0 + row)*4 + m)*256 + col] = val;
      }
  }
}

extern "C" void kernel_launch(void* const* d_in, const int* in_sizes, int n_in,
                              void* d_out, int out_size, void* d_ws, size_t ws_size,
                              hipStream_t stream){
  const float* x    = (const float*)d_in[0];
  const float* Wq   = (const float*)d_in[1];
  const float* bq   = (const float*)d_in[2];
  const float* Wk   = (const float*)d_in[3];
  const float* bk   = (const float*)d_in[4];
  const float* Wv   = (const float*)d_in[5];
  const float* bv   = (const float*)d_in[6];
  const float* Wo   = (const float*)d_in[7];
  const float* bo   = (const float*)d_in[8];
  const float* g1w  = (const float*)d_in[9];
  const float* g1b  = (const float*)d_in[10];
  const float* g2w  = (const float*)d_in[11];
  const float* g2b  = (const float*)d_in[12];
  const float* ln_g = (const float*)d_in[13];
  const float* ln_b = (const float*)d_in[14];
  const float* f1w  = (const float*)d_in[15];
  const float* f1b  = (const float*)d_in[16];
  const float* f2w  = (const float*)d_in[17];
  const float* f2bb = (const float*)d_in[18];

  float* out      = (float*)d_out;
  float* gate_out = out + (size_t)B_SZ * M_SZ * D_SZ;

  short* wsY = (short*)d_ws;
  short* wsW = (short*)d_ws + (size_t)B_SZ * M_SZ * D_SZ;   // bf16 y then bf16 weights

  hipLaunchKernelGGL(k_cast_w, dim3((NW_TOT + 255) / 256), dim3(256), 0, stream,
                     Wq, Wk, Wv, Wo, g1w, f1w, f2w, wsW);
  hipLaunchKernelGGL(k_attn, dim3(B_SZ / 16), dim3(512), 0, stream,
                     x, wsW, bq, bk, bv, bo, g1b, g2w, g2b, ln_g, ln_b, wsY, gate_out);
  hipLaunchKernelGGL(k_ff, dim3(4 * (B_SZ / 128)), dim3(512), 0, stream,
                     wsY, wsW, f1b, f2bb, out);
}